// Round 1
// baseline (404.187 us; speedup 1.0000x reference)
//
#include <hip/hip_runtime.h>
#include <hip/hip_bf16.h>

// B=4, N=2048, C=768, H=12, HD=64 ; tokens M = B*N = 8192
// qkv:  [8192][2304] = x @ qkv_w^T + qkv_b   (bf16, bias fused)
// attn: causal flash attention per (b,h), out -> [8192][768] bf16 (B,N,C layout)
// proj: out = attn_out @ proj_w^T + proj_b -> d_out fp32

typedef __attribute__((ext_vector_type(8))) short bf16x8;
typedef __attribute__((ext_vector_type(4))) float f32x4;

__device__ __forceinline__ unsigned short f2bf(float f) {
  unsigned u = __float_as_uint(f);
  unsigned rounding = 0x7FFFu + ((u >> 16) & 1u);
  return (unsigned short)((u + rounding) >> 16);
}

__global__ void cast_f32_to_bf16(const float* __restrict__ in,
                                 unsigned short* __restrict__ out, int n) {
  int idx = blockIdx.x * blockDim.x + threadIdx.x;
  int stride = gridDim.x * blockDim.x;
  for (int i = idx * 4; i < n; i += stride * 4) {
    float4 v = *reinterpret_cast<const float4*>(in + i);
    ushort4 o;
    o.x = f2bf(v.x); o.y = f2bf(v.y); o.z = f2bf(v.z); o.w = f2bf(v.w);
    *reinterpret_cast<ushort4*>(out + i) = o;
  }
}

// C[m][n] = sum_k A[m][k] * Bw[n][k] + bias[n]
// A: [M][K] bf16 row-major, Bw: [Ncols][K] bf16 row-major (the B^T-friendly case)
template <bool OUT_F32>
__global__ __launch_bounds__(256) void gemm_bt_kernel(
    const unsigned short* __restrict__ A,
    const unsigned short* __restrict__ Bw,
    const float* __restrict__ bias,
    void* __restrict__ Cout,
    int M, int Ncols, int K, int ldc) {
  __shared__ short As[128][40];  // +8 pad: row stride 80B (16B-aligned, ~2-way banks)
  __shared__ short Bs[128][40];

  const int t = threadIdx.x;
  const int lane = t & 63;
  const int wave = t >> 6;
  const int wm = wave >> 1;      // 2x2 waves over 128x128
  const int wn = wave & 1;
  const int m0 = blockIdx.y * 128;
  const int n0 = blockIdx.x * 128;

  const int lrow = lane & 15;
  const int lk = (lane >> 4) * 8;

  f32x4 acc[4][4] = {};

  const int srow = t >> 2;        // 0..63
  const int skc = (t & 3) * 8;    // 0,8,16,24

  for (int k0 = 0; k0 < K; k0 += 32) {
#pragma unroll
    for (int half = 0; half < 2; ++half) {
      int r = srow + half * 64;
      *reinterpret_cast<bf16x8*>(&As[r][skc]) =
          *reinterpret_cast<const bf16x8*>(A + (size_t)(m0 + r) * K + k0 + skc);
      *reinterpret_cast<bf16x8*>(&Bs[r][skc]) =
          *reinterpret_cast<const bf16x8*>(Bw + (size_t)(n0 + r) * K + k0 + skc);
    }
    __syncthreads();
    bf16x8 a[4], b[4];
#pragma unroll
    for (int m = 0; m < 4; ++m)
      a[m] = *reinterpret_cast<const bf16x8*>(&As[wm * 64 + m * 16 + lrow][lk]);
#pragma unroll
    for (int n = 0; n < 4; ++n)
      b[n] = *reinterpret_cast<const bf16x8*>(&Bs[wn * 64 + n * 16 + lrow][lk]);
#pragma unroll
    for (int m = 0; m < 4; ++m)
#pragma unroll
      for (int n = 0; n < 4; ++n)
        acc[m][n] = __builtin_amdgcn_mfma_f32_16x16x32_bf16(a[m], b[n], acc[m][n], 0, 0, 0);
    __syncthreads();
  }

  // C/D layout: col = lane&15, row = (lane>>4)*4 + reg
  const int orow0 = (lane >> 4) * 4;
  const int ocol = lane & 15;
#pragma unroll
  for (int m = 0; m < 4; ++m) {
#pragma unroll
    for (int n = 0; n < 4; ++n) {
      const int c = n0 + wn * 64 + n * 16 + ocol;
      const float bv = bias[c];
#pragma unroll
      for (int r = 0; r < 4; ++r) {
        const int rr = m0 + wm * 64 + m * 16 + orow0 + r;
        const float v = acc[m][n][r] + bv;
        if (OUT_F32)
          reinterpret_cast<float*>(Cout)[(size_t)rr * ldc + c] = v;
        else
          reinterpret_cast<unsigned short*>(Cout)[(size_t)rr * ldc + c] = f2bf(v);
      }
    }
  }
}

#define ATT_N 2048
#define ATT_H 12
#define ATT_HD 64
#define QKV_LD 2304

// grid: (32 q-blocks of 64 rows, 48 b*h). 256 threads = 4 waves x 16 q-rows.
__global__ __launch_bounds__(256) void attn_kernel(
    const unsigned short* __restrict__ qkv,  // [B*N][2304] bf16
    unsigned short* __restrict__ out) {      // [B*N][768]  bf16
  __shared__ short Ks[32][72];    // K tile [key][d], +8 pad
  __shared__ short Vt[64][40];    // V tile transposed [d][key], +8 pad
  __shared__ short Ps[4][16][40]; // per-wave P tile [qrow][key], +8 pad

  const int t = threadIdx.x;
  const int lane = t & 63;
  const int w = t >> 6;
  const int qb = blockIdx.x;  // 0..31
  const int bh = blockIdx.y;  // 0..47
  const int b = bh / ATT_H;
  const int h = bh % ATT_H;

  const size_t rowbase = (size_t)b * ATT_N;
  const unsigned short* qptr = qkv + rowbase * QKV_LD + h * ATT_HD;
  const unsigned short* kptr = qptr + 768;
  const unsigned short* vptr = qptr + 1536;

  const int lrow = lane & 15;
  const int lk = (lane >> 4) * 8;
  const int qbase = qb * 64 + w * 16;

  // Q fragments, A-layout: lane holds Q[qbase + (lane&15)][(lane>>4)*8 + r (+32*half)]
  bf16x8 qf[2];
#pragma unroll
  for (int hf = 0; hf < 2; ++hf)
    qf[hf] = *reinterpret_cast<const bf16x8*>(
        qptr + (size_t)(qbase + lrow) * QKV_LD + hf * 32 + lk);

  f32x4 O[4] = {};
  float mrun[4], lrun[4];
#pragma unroll
  for (int r = 0; r < 4; ++r) { mrun[r] = -1e30f; lrun[r] = 0.f; }

  const int nt = qb * 2 + 2;  // causal: tiles of 32 keys
  const int qrow0 = (lane >> 4) * 4;
  const float scale = 0.125f;

  const int skey = t >> 3;       // 0..31
  const int sdc = (t & 7) * 8;   // 0..56

  for (int kt0 = 0; kt0 < nt; ++kt0) {
    const int k0 = kt0 * 32;
    // stage K [key][d]
    *reinterpret_cast<bf16x8*>(&Ks[skey][sdc]) =
        *reinterpret_cast<const bf16x8*>(kptr + (size_t)(k0 + skey) * QKV_LD + sdc);
    // stage V transposed [d][key]
    bf16x8 vv = *reinterpret_cast<const bf16x8*>(vptr + (size_t)(k0 + skey) * QKV_LD + sdc);
#pragma unroll
    for (int j = 0; j < 8; ++j) Vt[sdc + j][skey] = vv[j];
    __syncthreads();

    // S = Q @ K^T  (two 16-key column tiles, chained over d halves)
    f32x4 sf[2];
#pragma unroll
    for (int kt = 0; kt < 2; ++kt) {
      bf16x8 kf0 = *reinterpret_cast<const bf16x8*>(&Ks[kt * 16 + lrow][lk]);
      bf16x8 kf1 = *reinterpret_cast<const bf16x8*>(&Ks[kt * 16 + lrow][32 + lk]);
      f32x4 z = {};
      z = __builtin_amdgcn_mfma_f32_16x16x32_bf16(qf[0], kf0, z, 0, 0, 0);
      sf[kt] = __builtin_amdgcn_mfma_f32_16x16x32_bf16(qf[1], kf1, z, 0, 0, 0);
    }

    // scale + causal mask + row max (rows live across 16 lanes of same quarter)
    float p[2][4];
    float tmax[4];
#pragma unroll
    for (int r = 0; r < 4; ++r) {
      const int qg = qbase + qrow0 + r;
#pragma unroll
      for (int kt = 0; kt < 2; ++kt) {
        const int kg = k0 + kt * 16 + lrow;
        float s = sf[kt][r] * scale;
        p[kt][r] = (kg > qg) ? -1e30f : s;
      }
      tmax[r] = fmaxf(p[0][r], p[1][r]);
#pragma unroll
      for (int off = 1; off < 16; off <<= 1)
        tmax[r] = fmaxf(tmax[r], __shfl_xor(tmax[r], off, 16));
    }

    float corr[4];
#pragma unroll
    for (int r = 0; r < 4; ++r) {
      const float mn = fmaxf(mrun[r], tmax[r]);
      corr[r] = __expf(mrun[r] - mn);
      mrun[r] = mn;
      float rs = 0.f;
#pragma unroll
      for (int kt = 0; kt < 2; ++kt) {
        p[kt][r] = __expf(p[kt][r] - mn);
        rs += p[kt][r];
      }
#pragma unroll
      for (int off = 1; off < 16; off <<= 1) rs += __shfl_xor(rs, off, 16);
      lrun[r] = lrun[r] * corr[r] + rs;
    }
#pragma unroll
    for (int n = 0; n < 4; ++n)
#pragma unroll
      for (int r = 0; r < 4; ++r) O[n][r] *= corr[r];

    // P -> LDS (bf16), per-wave private region, then re-fragment as A-operand
#pragma unroll
    for (int kt = 0; kt < 2; ++kt)
#pragma unroll
      for (int r = 0; r < 4; ++r)
        Ps[w][qrow0 + r][kt * 16 + lrow] = (short)f2bf(p[kt][r]);

    bf16x8 pa = *reinterpret_cast<const bf16x8*>(&Ps[w][lrow][lk]);
#pragma unroll
    for (int n = 0; n < 4; ++n) {
      bf16x8 bv = *reinterpret_cast<const bf16x8*>(&Vt[n * 16 + lrow][lk]);
      O[n] = __builtin_amdgcn_mfma_f32_16x16x32_bf16(pa, bv, O[n], 0, 0, 0);
    }
    __syncthreads();
  }

  // epilogue: O /= l, write bf16 (B,N,C) rows
#pragma unroll
  for (int n = 0; n < 4; ++n) {
#pragma unroll
    for (int r = 0; r < 4; ++r) {
      const int qg = qbase + qrow0 + r;
      const float v = O[n][r] / lrun[r];
      out[(rowbase + qg) * 768 + h * ATT_HD + n * 16 + lrow] = f2bf(v);
    }
  }
}

extern "C" void kernel_launch(void* const* d_in, const int* in_sizes, int n_in,
                              void* d_out, int out_size, void* d_ws, size_t ws_size,
                              hipStream_t stream) {
  const float* x = (const float*)d_in[0];
  const float* qkv_w = (const float*)d_in[1];
  const float* qkv_b = (const float*)d_in[2];
  const float* proj_w = (const float*)d_in[3];
  const float* proj_b = (const float*)d_in[4];
  float* out = (float*)d_out;

  unsigned short* x_bf = (unsigned short*)d_ws;            // 8192*768
  unsigned short* qw_bf = x_bf + (size_t)8192 * 768;       // 2304*768
  unsigned short* pw_bf = qw_bf + (size_t)2304 * 768;      // 768*768
  unsigned short* qkv = pw_bf + (size_t)768 * 768;         // 8192*2304
  unsigned short* attno = qkv + (size_t)8192 * 2304;       // 8192*768

  cast_f32_to_bf16<<<dim3(1024), dim3(256), 0, stream>>>(x, x_bf, 8192 * 768);
  cast_f32_to_bf16<<<dim3(512), dim3(256), 0, stream>>>(qkv_w, qw_bf, 2304 * 768);
  cast_f32_to_bf16<<<dim3(256), dim3(256), 0, stream>>>(proj_w, pw_bf, 768 * 768);

  gemm_bt_kernel<false><<<dim3(18, 64), dim3(256), 0, stream>>>(
      x_bf, qw_bf, qkv_b, qkv, 8192, 2304, 768, 2304);
  attn_kernel<<<dim3(32, 48), dim3(256), 0, stream>>>(qkv, attno);
  gemm_bt_kernel<true><<<dim3(6, 64), dim3(256), 0, stream>>>(
      attno, pw_bf, proj_b, out, 8192, 768, 768, 768);
}

// Round 4
// 179.672 us; speedup vs baseline: 2.2496x; 2.2496x over previous
//
#include <hip/hip_runtime.h>
#include <hip/hip_bf16.h>

// B=4, N=2048, C=768, H=12, HD=64 ; tokens M = B*N = 8192
// qkv:  [8192][2304] = x @ qkv_w^T + qkv_b   (bf16, bias fused)
// attn: causal flash attention per (b,h), swapped-QKT 32x32 MFMA structure
// proj: out = attn_out @ proj_w^T + proj_b -> d_out fp32

typedef __attribute__((ext_vector_type(8))) short bf16x8;
typedef __attribute__((ext_vector_type(4))) float f32x4;
typedef __attribute__((ext_vector_type(16))) float f32x16;

__device__ __forceinline__ unsigned short f2bf(float f) {
  unsigned u = __float_as_uint(f);
  unsigned rounding = 0x7FFFu + ((u >> 16) & 1u);
  return (unsigned short)((u + rounding) >> 16);
}

__global__ void cast_f32_to_bf16(const float* __restrict__ in,
                                 unsigned short* __restrict__ out, int n) {
  int idx = blockIdx.x * blockDim.x + threadIdx.x;
  int stride = gridDim.x * blockDim.x;
  for (int i = idx * 4; i < n; i += stride * 4) {
    float4 v = *reinterpret_cast<const float4*>(in + i);
    ushort4 o;
    o.x = f2bf(v.x); o.y = f2bf(v.y); o.z = f2bf(v.z); o.w = f2bf(v.w);
    *reinterpret_cast<ushort4*>(out + i) = o;
  }
}

// C[m][n] = sum_k A[m][k] * Bw[n][k] + bias[n]
template <bool OUT_F32>
__global__ __launch_bounds__(256) void gemm_bt_kernel(
    const unsigned short* __restrict__ A,
    const unsigned short* __restrict__ Bw,
    const float* __restrict__ bias,
    void* __restrict__ Cout,
    int M, int Ncols, int K, int ldc) {
  __shared__ short As[128][40];
  __shared__ short Bs[128][40];

  const int t = threadIdx.x;
  const int lane = t & 63;
  const int wave = t >> 6;
  const int wm = wave >> 1;
  const int wn = wave & 1;
  const int m0 = blockIdx.y * 128;
  const int n0 = blockIdx.x * 128;

  const int lrow = lane & 15;
  const int lk = (lane >> 4) * 8;

  f32x4 acc[4][4] = {};

  const int srow = t >> 2;
  const int skc = (t & 3) * 8;

  for (int k0 = 0; k0 < K; k0 += 32) {
#pragma unroll
    for (int half = 0; half < 2; ++half) {
      int r = srow + half * 64;
      *reinterpret_cast<bf16x8*>(&As[r][skc]) =
          *reinterpret_cast<const bf16x8*>(A + (size_t)(m0 + r) * K + k0 + skc);
      *reinterpret_cast<bf16x8*>(&Bs[r][skc]) =
          *reinterpret_cast<const bf16x8*>(Bw + (size_t)(n0 + r) * K + k0 + skc);
    }
    __syncthreads();
    bf16x8 a[4], b[4];
#pragma unroll
    for (int m = 0; m < 4; ++m)
      a[m] = *reinterpret_cast<const bf16x8*>(&As[wm * 64 + m * 16 + lrow][lk]);
#pragma unroll
    for (int n = 0; n < 4; ++n)
      b[n] = *reinterpret_cast<const bf16x8*>(&Bs[wn * 64 + n * 16 + lrow][lk]);
#pragma unroll
    for (int m = 0; m < 4; ++m)
#pragma unroll
      for (int n = 0; n < 4; ++n)
        acc[m][n] = __builtin_amdgcn_mfma_f32_16x16x32_bf16(a[m], b[n], acc[m][n], 0, 0, 0);
    __syncthreads();
  }

  const int orow0 = (lane >> 4) * 4;
  const int ocol = lane & 15;
#pragma unroll
  for (int m = 0; m < 4; ++m) {
#pragma unroll
    for (int n = 0; n < 4; ++n) {
      const int c = n0 + wn * 64 + n * 16 + ocol;
      const float bv = bias[c];
#pragma unroll
      for (int r = 0; r < 4; ++r) {
        const int rr = m0 + wm * 64 + m * 16 + orow0 + r;
        const float v = acc[m][n][r] + bv;
        if (OUT_F32)
          reinterpret_cast<float*>(Cout)[(size_t)rr * ldc + c] = v;
        else
          reinterpret_cast<unsigned short*>(Cout)[(size_t)rr * ldc + c] = f2bf(v);
      }
    }
  }
}

#define ATT_N 2048
#define ATT_H 12
#define QKV_LD 2304

// Swapped-QKT flash attention.
// Block: 256 thr = 4 waves x 32 q-rows = 128 q-rows. KV tile = 64 keys.
// Grid: 768 = 16 qblocks x 48 bh, heavy-first (qb descending).
// Per wave: S^T = mfma32x32x16(K, Q) -> lane holds S^T[keys][q=lane&31]
//   (16 keys in regs, partner lane^32 has the other 16). Softmax = in-reg
//   reduce + 1 shfl_xor(32). P^T repacked in-reg into PV's B-operand.
// O^T[d][q] = mfma(V^T_frag, P^T_frag). V^T, K staged in LDS fragment-major
//   (frag*1024B + lane*16B) -> conflict-free ds_read_b128.
__global__ __launch_bounds__(256) void attn_kernel(
    const unsigned short* __restrict__ qkv,  // [B*N][2304] bf16
    unsigned short* __restrict__ out) {      // [B*N][768]  bf16
  __shared__ short Ks[4096];  // 8 frags * 64 lanes * 8 shorts (K[key][d] fragments)
  __shared__ short Vs[4096];  // 8 frags (V^T[d][key] fragments)

  const int t = threadIdx.x;
  const int lane = t & 63;
  const int w = t >> 6;
  const int hi = lane >> 5;
  const int l31 = lane & 31;

  const int wid = blockIdx.x;
  const int qb = 15 - (wid / 48);   // heavy blocks first
  const int bh = wid % 48;          // all 16 blocks of a bh land on XCD bh%8
  const int b = bh / ATT_H;
  const int h = bh % ATT_H;

  const size_t rowbase = (size_t)b * ATT_N;
  const unsigned short* qptr = qkv + rowbase * QKV_LD + h * 64;
  const unsigned short* kptr = qptr + 768;
  const unsigned short* vptr = qptr + 1536;

  const int q0w = qb * 128 + w * 32;   // wave's q-row base
  const int qg = q0w + l31;            // this lane's q row

  // Q as B-operand: lane holds Q[q=lane&31][d = dk*16 + hi*8 + j]
  bf16x8 qf[4];
#pragma unroll
  for (int dk = 0; dk < 4; ++dk)
    qf[dk] = *reinterpret_cast<const bf16x8*>(
        qptr + (size_t)(q0w + l31) * QKV_LD + dk * 16 + hi * 8);

  f32x16 O0 = {}, O1 = {};   // O^T[d][q]: d-halves 0..31 / 32..63
  float mrun = -1e30f, lrun = 0.f;

  const int nt = (qb + 1) * 2;

  // staging: 512 chunks (64 rows x 8 x 8-elem) per matrix; 2 chunks/thread
  const int c0 = t, c1 = t + 256;
  const int kr0 = c0 >> 3, c80 = c0 & 7;
  const int kr1 = c1 >> 3, c81 = c1 & 7;

  bf16x8 gk0, gk1, gv0, gv1;
  auto prefetch = [&](int k0) {
    gk0 = *reinterpret_cast<const bf16x8*>(kptr + (size_t)(k0 + kr0) * QKV_LD + c80 * 8);
    gk1 = *reinterpret_cast<const bf16x8*>(kptr + (size_t)(k0 + kr1) * QKV_LD + c81 * 8);
    gv0 = *reinterpret_cast<const bf16x8*>(vptr + (size_t)(k0 + kr0) * QKV_LD + c80 * 8);
    gv1 = *reinterpret_cast<const bf16x8*>(vptr + (size_t)(k0 + kr1) * QKV_LD + c81 * 8);
  };

  prefetch(0);

  for (int kt = 0; kt < nt; ++kt) {
    const int k0 = kt * 64;
    __syncthreads();  // previous tile's LDS reads done
    {
      // K chunk (key,8d) -> frag = (key>>5)*4 + d8>>1 ; lane = key&31 + 32*(d8&1)
      int s0 = (((kr0 >> 5) * 4 + (c80 >> 1)) * 64 + (kr0 & 31) + 32 * (c80 & 1)) * 8;
      *reinterpret_cast<bf16x8*>(&Ks[s0]) = gk0;
      int s1 = (((kr1 >> 5) * 4 + (c81 >> 1)) * 64 + (kr1 & 31) + 32 * (c81 & 1)) * 8;
      *reinterpret_cast<bf16x8*>(&Ks[s1]) = gk1;
      // V element (key,d) -> frag = (d>>5)*4 + key>>4 ; lane = d&31 + 32*((key>>3)&1); j = key&7
#pragma unroll
      for (int jj = 0; jj < 8; ++jj) {
        int d0 = c80 * 8 + jj;
        Vs[(((d0 >> 5) * 4 + (kr0 >> 4)) * 64 + (d0 & 31) + 32 * ((kr0 >> 3) & 1)) * 8 + (kr0 & 7)] = gv0[jj];
        int d1 = c81 * 8 + jj;
        Vs[(((d1 >> 5) * 4 + (kr1 >> 4)) * 64 + (d1 & 31) + 32 * ((kr1 >> 3) & 1)) * 8 + (kr1 & 7)] = gv1[jj];
      }
    }
    __syncthreads();
    if (kt + 1 < nt) prefetch(k0 + 64);

    if (k0 <= q0w + 31) {  // wave has unmasked work in this tile
      // S^T[key][q] = sum_d K[key][d] Q[q][d]
      f32x16 S0 = {}, S1 = {};
      __builtin_amdgcn_s_setprio(1);
#pragma unroll
      for (int dk = 0; dk < 4; ++dk) {
        bf16x8 kf = *reinterpret_cast<const bf16x8*>(&Ks[(dk * 64 + lane) * 8]);
        S0 = __builtin_amdgcn_mfma_f32_32x32x16_bf16(kf, qf[dk], S0, 0, 0, 0);
      }
#pragma unroll
      for (int dk = 0; dk < 4; ++dk) {
        bf16x8 kf = *reinterpret_cast<const bf16x8*>(&Ks[((4 + dk) * 64 + lane) * 8]);
        S1 = __builtin_amdgcn_mfma_f32_32x32x16_bf16(kf, qf[dk], S1, 0, 0, 0);
      }
      __builtin_amdgcn_s_setprio(0);

      // scale + causal mask. key(reg r) = k0 + 32s + (r&3) + 8*(r>>2) + 4*hi
      const float scale = 0.125f;
      float p0[16], p1[16];
      if (k0 + 63 <= q0w) {  // fully unmasked for every lane of this wave
#pragma unroll
        for (int r = 0; r < 16; ++r) { p0[r] = S0[r] * scale; p1[r] = S1[r] * scale; }
      } else {
#pragma unroll
        for (int r = 0; r < 16; ++r) {
          int row = (r & 3) + 8 * (r >> 2) + 4 * hi;
          p0[r] = (k0 + row > qg) ? -1e30f : S0[r] * scale;
          p1[r] = (k0 + 32 + row > qg) ? -1e30f : S1[r] * scale;
        }
      }

      float tmax = p0[0];
#pragma unroll
      for (int r = 1; r < 16; ++r) tmax = fmaxf(tmax, p0[r]);
#pragma unroll
      for (int r = 0; r < 16; ++r) tmax = fmaxf(tmax, p1[r]);
      tmax = fmaxf(tmax, __shfl_xor(tmax, 32));

      const float mnew = fmaxf(mrun, tmax);
      const float corr = __expf(mrun - mnew);
      mrun = mnew;
      float rsum = 0.f;
#pragma unroll
      for (int r = 0; r < 16; ++r) { p0[r] = __expf(p0[r] - mnew); rsum += p0[r]; }
#pragma unroll
      for (int r = 0; r < 16; ++r) { p1[r] = __expf(p1[r] - mnew); rsum += p1[r]; }
      rsum += __shfl_xor(rsum, 32);
      lrun = lrun * corr + rsum;
#pragma unroll
      for (int r = 0; r < 16; ++r) { O0[r] *= corr; O1[r] *= corr; }

      // pack P -> bf16 pairs: pu[m][c] holds keys (32s + 8m + 4hi + 2c, +1)
      unsigned pu0[4][2], pu1[4][2];
#pragma unroll
      for (int m = 0; m < 4; ++m)
#pragma unroll
        for (int c = 0; c < 2; ++c) {
          pu0[m][c] = (unsigned)f2bf(p0[4 * m + 2 * c]) | ((unsigned)f2bf(p0[4 * m + 2 * c + 1]) << 16);
          pu1[m][c] = (unsigned)f2bf(p1[4 * m + 2 * c]) | ((unsigned)f2bf(p1[4 * m + 2 * c + 1]) << 16);
        }

      // Build PV B-operand frags: lane needs keys 16*ks + 8*hi + {0..7}.
      // j=0..3 from half-0's u[2t+hi], j=4..7 from half-1's u[2t+hi].
      __builtin_amdgcn_s_setprio(1);
#pragma unroll
      for (int s = 0; s < 2; ++s) {
        const unsigned (&pu)[4][2] = s ? pu1 : pu0;
#pragma unroll
        for (int tt = 0; tt < 2; ++tt) {
          unsigned s0v = hi ? pu[2 * tt][0] : pu[2 * tt + 1][0];
          unsigned s1v = hi ? pu[2 * tt][1] : pu[2 * tt + 1][1];
          unsigned r0 = __shfl_xor(s0v, 32);
          unsigned r1 = __shfl_xor(s1v, 32);
          union { unsigned u[4]; bf16x8 v; } U;
          U.u[0] = hi ? r0 : pu[2 * tt][0];
          U.u[1] = hi ? r1 : pu[2 * tt][1];
          U.u[2] = hi ? pu[2 * tt + 1][0] : r0;
          U.u[3] = hi ? pu[2 * tt + 1][1] : r1;
          const int ks = s * 2 + tt;
          bf16x8 vf0 = *reinterpret_cast<const bf16x8*>(&Vs[(ks * 64 + lane) * 8]);
          O0 = __builtin_amdgcn_mfma_f32_32x32x16_bf16(vf0, U.v, O0, 0, 0, 0);
          bf16x8 vf1 = *reinterpret_cast<const bf16x8*>(&Vs[((4 + ks) * 64 + lane) * 8]);
          O1 = __builtin_amdgcn_mfma_f32_32x32x16_bf16(vf1, U.v, O1, 0, 0, 0);
        }
      }
      __builtin_amdgcn_s_setprio(0);
    }
  }

  // epilogue: O^T[d][q=lane&31] -> out rows; d = 32*half + 8m + 4hi + i
  const float inv = 1.0f / lrun;
  unsigned short* orow = out + (rowbase + q0w + l31) * 768 + h * 64;
#pragma unroll
  for (int half = 0; half < 2; ++half) {
    const f32x16& O = half ? O1 : O0;
#pragma unroll
    for (int m = 0; m < 4; ++m) {
      ushort4 o4;
      o4.x = f2bf(O[4 * m + 0] * inv);
      o4.y = f2bf(O[4 * m + 1] * inv);
      o4.z = f2bf(O[4 * m + 2] * inv);
      o4.w = f2bf(O[4 * m + 3] * inv);
      *reinterpret_cast<ushort4*>(orow + half * 32 + 8 * m + 4 * hi) = o4;
    }
  }
}

extern "C" void kernel_launch(void* const* d_in, const int* in_sizes, int n_in,
                              void* d_out, int out_size, void* d_ws, size_t ws_size,
                              hipStream_t stream) {
  const float* x = (const float*)d_in[0];
  const float* qkv_w = (const float*)d_in[1];
  const float* qkv_b = (const float*)d_in[2];
  const float* proj_w = (const float*)d_in[3];
  const float* proj_b = (const float*)d_in[4];
  float* out = (float*)d_out;

  unsigned short* x_bf = (unsigned short*)d_ws;            // 8192*768
  unsigned short* qw_bf = x_bf + (size_t)8192 * 768;       // 2304*768
  unsigned short* pw_bf = qw_bf + (size_t)2304 * 768;      // 768*768
  unsigned short* qkv = pw_bf + (size_t)768 * 768;         // 8192*2304
  unsigned short* attno = qkv + (size_t)8192 * 2304;       // 8192*768

  cast_f32_to_bf16<<<dim3(1024), dim3(256), 0, stream>>>(x, x_bf, 8192 * 768);
  cast_f32_to_bf16<<<dim3(512), dim3(256), 0, stream>>>(qkv_w, qw_bf, 2304 * 768);
  cast_f32_to_bf16<<<dim3(256), dim3(256), 0, stream>>>(proj_w, pw_bf, 768 * 768);

  gemm_bt_kernel<false><<<dim3(18, 64), dim3(256), 0, stream>>>(
      x_bf, qw_bf, qkv_b, qkv, 8192, 2304, 768, 2304);
  attn_kernel<<<dim3(768), dim3(256), 0, stream>>>(qkv, attno);
  gemm_bt_kernel<true><<<dim3(6, 64), dim3(256), 0, stream>>>(
      attno, pw_bf, proj_b, out, 8192, 768, 768, 768);
}

// Round 7
// 161.841 us; speedup vs baseline: 2.4974x; 1.1102x over previous
//
#include <hip/hip_runtime.h>
#include <hip/hip_bf16.h>

// B=4, N=2048, C=768, H=12, HD=64 ; tokens M = B*N = 8192
// qkv:  [8192][2304] = x @ qkv_w^T + qkv_b   (bf16, bias fused)
// vt:   V transposed per head -> Vt[bh][d][key]
// attn: causal flash attention, swapped-QKT 32x32 MFMA, gload_lds staging
// proj: out = attn_out @ proj_w^T + proj_b -> d_out fp32

typedef __attribute__((ext_vector_type(8))) short bf16x8;
typedef __attribute__((ext_vector_type(4))) float f32x4;
typedef __attribute__((ext_vector_type(16))) float f32x16;

typedef __attribute__((address_space(3))) unsigned int lds_uint;
typedef __attribute__((address_space(1))) const unsigned int gbl_uint;

__device__ __forceinline__ void gload16(const void* g, void* l) {
  __builtin_amdgcn_global_load_lds((gbl_uint*)g, (lds_uint*)l, 16, 0, 0);
}

__device__ __forceinline__ unsigned short f2bf(float f) {
  unsigned u = __float_as_uint(f);
  unsigned rounding = 0x7FFFu + ((u >> 16) & 1u);
  return (unsigned short)((u + rounding) >> 16);
}

__device__ __forceinline__ unsigned cvtpk(float lo, float hi) {
  unsigned r;
  asm("v_cvt_pk_bf16_f32 %0, %1, %2" : "=v"(r) : "v"(lo), "v"(hi));
  return r;
}

__device__ __forceinline__ float exp2a(float x) {
  float r;
  asm("v_exp_f32 %0, %1" : "=v"(r) : "v"(x));
  return r;
}

__global__ void cast_f32_to_bf16(const float* __restrict__ in,
                                 unsigned short* __restrict__ out, int n) {
  int idx = blockIdx.x * blockDim.x + threadIdx.x;
  int stride = gridDim.x * blockDim.x;
  for (int i = idx * 4; i < n; i += stride * 4) {
    float4 v = *reinterpret_cast<const float4*>(in + i);
    ushort4 o;
    o.x = f2bf(v.x); o.y = f2bf(v.y); o.z = f2bf(v.z); o.w = f2bf(v.w);
    *reinterpret_cast<ushort4*>(out + i) = o;
  }
}

// C[m][n] = sum_k A[m][k] * Bw[n][k] + bias[n]; gload_lds double-buffered
template <bool OUT_F32>
__global__ __launch_bounds__(256) void gemm_bt_kernel(
    const unsigned short* __restrict__ A,
    const unsigned short* __restrict__ Bw,
    const float* __restrict__ bias,
    void* __restrict__ Cout,
    int M, int Ncols, int K, int ldc) {
  __shared__ __align__(16) short As[2][4096];  // [buf][128 rows x 32 k]
  __shared__ __align__(16) short Bs[2][4096];

  const int t = threadIdx.x;
  const int lane = t & 63;
  const int wave = t >> 6;
  const int wm = wave >> 1;
  const int wn = wave & 1;
  const int m0 = blockIdx.y * 128;
  const int n0 = blockIdx.x * 128;
  const int lrow = lane & 15;
  const int lk = (lane >> 4) * 8;

  // staging: thread chunk0 = row t>>2, cols (t&3)*8; chunk1 = row+64
  const int srow = t >> 2, scol = (t & 3) * 8;
  const unsigned short* gA0 = A + (size_t)(m0 + srow) * K + scol;
  const unsigned short* gA1 = gA0 + (size_t)64 * K;
  const unsigned short* gB0 = Bw + (size_t)(n0 + srow) * K + scol;
  const unsigned short* gB1 = gB0 + (size_t)64 * K;
  const int db0 = wave * 512, db1 = 2048 + wave * 512;

  f32x4 acc[4][4] = {};
  const int nk = K / 32;

  gload16(gA0, &As[0][db0]); gload16(gA1, &As[0][db1]);
  gload16(gB0, &Bs[0][db0]); gload16(gB1, &Bs[0][db1]);

  int cur = 0;
  for (int kk = 0; kk < nk; ++kk) {
    __syncthreads();  // drains vmcnt: buf[cur] ready, buf[cur^1] reads done
    if (kk + 1 < nk) {
      const int off = (kk + 1) * 32;
      gload16(gA0 + off, &As[cur ^ 1][db0]); gload16(gA1 + off, &As[cur ^ 1][db1]);
      gload16(gB0 + off, &Bs[cur ^ 1][db0]); gload16(gB1 + off, &Bs[cur ^ 1][db1]);
    }
    bf16x8 a[4], b[4];
#pragma unroll
    for (int m = 0; m < 4; ++m)
      a[m] = *reinterpret_cast<const bf16x8*>(&As[cur][(wm * 64 + m * 16 + lrow) * 32 + lk]);
#pragma unroll
    for (int n = 0; n < 4; ++n)
      b[n] = *reinterpret_cast<const bf16x8*>(&Bs[cur][(wn * 64 + n * 16 + lrow) * 32 + lk]);
#pragma unroll
    for (int m = 0; m < 4; ++m)
#pragma unroll
      for (int n = 0; n < 4; ++n)
        acc[m][n] = __builtin_amdgcn_mfma_f32_16x16x32_bf16(a[m], b[n], acc[m][n], 0, 0, 0);
    cur ^= 1;
  }

  const int orow0 = (lane >> 4) * 4;
  const int ocol = lane & 15;
#pragma unroll
  for (int m = 0; m < 4; ++m) {
#pragma unroll
    for (int n = 0; n < 4; ++n) {
      const int c = n0 + wn * 64 + n * 16 + ocol;
      const float bv = bias[c];
#pragma unroll
      for (int r = 0; r < 4; ++r) {
        const int rr = m0 + wm * 64 + m * 16 + orow0 + r;
        const float v = acc[m][n][r] + bv;
        if (OUT_F32)
          reinterpret_cast<float*>(Cout)[(size_t)rr * ldc + c] = v;
        else
          reinterpret_cast<unsigned short*>(Cout)[(size_t)rr * ldc + c] = f2bf(v);
      }
    }
  }
}

#define ATT_N 2048
#define ATT_H 12
#define QKV_LD 2304

// Vt[bh][d][key] <- qkv[b*2048+key][1536 + h*64 + d]
__global__ __launch_bounds__(256) void transpose_v(
    const unsigned short* __restrict__ qkv, unsigned short* __restrict__ vt) {
  const int kb = blockIdx.x;     // 0..7 (256 keys each)
  const int bh = blockIdx.y;     // 0..47
  const int t = threadIdx.x;
  const int b = bh / ATT_H, h = bh % ATT_H;
  const int d0 = (t & 7) * 8;
  const unsigned short* src = qkv + (size_t)(b * ATT_N) * QKV_LD + 1536 + h * 64 + d0;
  unsigned short* dst = vt + (size_t)bh * 64 * ATT_N + kb * 256;
#pragma unroll
  for (int kk = 0; kk < 8; ++kk) {
    const int ko = (t >> 3) + kk * 32;          // key within this 256-block
    bf16x8 v = *reinterpret_cast<const bf16x8*>(src + (size_t)(kb * 256 + ko) * QKV_LD);
#pragma unroll
    for (int j = 0; j < 8; ++j)
      dst[(size_t)(d0 + j) * ATT_N + ko] = v[j];
  }
}

// Swapped-QKT flash attention. 4 waves x 32 q-rows; KV tile 64; dbuf LDS.
// K frag layout (chunk i -> LDS elems 8i..8i+7): frag f=i>>6, lslot ls=i&63;
//   inverse: key=(f>>2)*32+(ls&31), dchunk=(f&3)*2+(ls>>5). Lane l at frag dk
//   holds K[key=l&31 (+32 for S1)][d = dk*16 + (l>>5)*8 + j] = MFMA A-frag.
// V^T staged identically from Vt (roles key<->d swapped): frag half*4+ks,
//   lane l holds V[key = k0+ks*16+(l>>5)*8+j][d = half*32 + (l&31)] = A-frag.
__global__ __launch_bounds__(256) void attn_kernel(
    const unsigned short* __restrict__ qkv,  // [B*N][2304] bf16
    const unsigned short* __restrict__ vt,   // [48][64][2048] bf16
    unsigned short* __restrict__ out) {      // [B*N][768]  bf16
  __shared__ __align__(16) short Ks[2][4096];
  __shared__ __align__(16) short Vs[2][4096];

  const int t = threadIdx.x;
  const int lane = t & 63;
  const int w = t >> 6;
  const int hi = lane >> 5;
  const int l31 = lane & 31;

  const int wid = blockIdx.x;
  const int qb = 15 - (wid / 48);   // heavy blocks first
  const int bh = wid % 48;
  const int b = bh / ATT_H;
  const int h = bh % ATT_H;

  const size_t rowbase = (size_t)b * ATT_N;
  const unsigned short* qptr = qkv + rowbase * QKV_LD + h * 64;
  const unsigned short* kptr = qptr + 768;
  const unsigned short* vtptr = vt + (size_t)bh * 64 * ATT_N;

  const int q0w = qb * 128 + w * 32;
  const int qg = q0w + l31;

  // Q as B-operand: lane holds Q[q=lane&31][d = dk*16 + hi*8 + j]
  bf16x8 qf[4];
#pragma unroll
  for (int dk = 0; dk < 4; ++dk)
    qf[dk] = *reinterpret_cast<const bf16x8*>(
        qptr + (size_t)(q0w + l31) * QKV_LD + dk * 16 + hi * 8);

  f32x16 O0 = {}, O1 = {};
  float mrun = -1e30f, lrun = 0.f;
  const int nt = (qb + 1) * 2;

  // inverse chunk->global mapping for gload_lds (dest elem = i*8)
  int kKr[2], kKc[2];
#pragma unroll
  for (int c = 0; c < 2; ++c) {
    const int i = t + c * 256;
    const int f = i >> 6, ls = i & 63;
    kKr[c] = (f >> 2) * 32 + (ls & 31);
    kKc[c] = (f & 3) * 2 + (ls >> 5);
  }
  const unsigned short* gK0 = kptr + (size_t)kKr[0] * QKV_LD + kKc[0] * 8;
  const unsigned short* gK1 = kptr + (size_t)kKr[1] * QKV_LD + kKc[1] * 8;
  // V^T: same frag mapping, row = d (stride ATT_N), col-chunk = keys
  const unsigned short* gV0 = vtptr + (size_t)kKr[0] * ATT_N + kKc[0] * 8;
  const unsigned short* gV1 = vtptr + (size_t)kKr[1] * ATT_N + kKc[1] * 8;
  const int db0 = w * 512, db1 = 2048 + w * 512;

  // prologue: stage tile 0 into buf 0
  gload16(gK0, &Ks[0][db0]); gload16(gK1, &Ks[0][db1]);
  gload16(gV0, &Vs[0][db0]); gload16(gV1, &Vs[0][db1]);

  int cur = 0;
  for (int kt = 0; kt < nt; ++kt) {
    const int k0 = kt * 64;
    __syncthreads();  // vmcnt drain: buf[cur] ready; prev reads of buf[cur^1] done
    if (kt + 1 < nt) {
      const size_t advk = (size_t)(k0 + 64) * QKV_LD;
      gload16(gK0 + advk, &Ks[cur ^ 1][db0]); gload16(gK1 + advk, &Ks[cur ^ 1][db1]);
      gload16(gV0 + (k0 + 64), &Vs[cur ^ 1][db0]);
      gload16(gV1 + (k0 + 64), &Vs[cur ^ 1][db1]);
    }

    if (k0 <= q0w + 31) {  // wave has unmasked work in this tile
      // S^T[key][q] = sum_d K[key][d] Q[q][d]
      f32x16 S0 = {}, S1 = {};
      __builtin_amdgcn_s_setprio(1);
#pragma unroll
      for (int dk = 0; dk < 4; ++dk) {
        bf16x8 kf = *reinterpret_cast<const bf16x8*>(&Ks[cur][(dk * 64 + lane) * 8]);
        S0 = __builtin_amdgcn_mfma_f32_32x32x16_bf16(kf, qf[dk], S0, 0, 0, 0);
      }
#pragma unroll
      for (int dk = 0; dk < 4; ++dk) {
        bf16x8 kf = *reinterpret_cast<const bf16x8*>(&Ks[cur][((4 + dk) * 64 + lane) * 8]);
        S1 = __builtin_amdgcn_mfma_f32_32x32x16_bf16(kf, qf[dk], S1, 0, 0, 0);
      }
      __builtin_amdgcn_s_setprio(0);

      // scale (exp2 domain) + causal mask. key(r) = k0 + 32s + (r&3)+8*(r>>2)+4*hi
      const float scale2 = 0.18033688f;  // 0.125 * log2(e)
      float p0[16], p1[16];
      if (k0 + 63 <= q0w) {
#pragma unroll
        for (int r = 0; r < 16; ++r) { p0[r] = S0[r] * scale2; p1[r] = S1[r] * scale2; }
      } else {
#pragma unroll
        for (int r = 0; r < 16; ++r) {
          int row = (r & 3) + 8 * (r >> 2) + 4 * hi;
          p0[r] = (k0 + row > qg) ? -1e30f : S0[r] * scale2;
          p1[r] = (k0 + 32 + row > qg) ? -1e30f : S1[r] * scale2;
        }
      }

      float tmax = p0[0];
#pragma unroll
      for (int r = 1; r < 16; ++r) tmax = fmaxf(tmax, p0[r]);
#pragma unroll
      for (int r = 0; r < 16; ++r) tmax = fmaxf(tmax, p1[r]);
      tmax = fmaxf(tmax, __shfl_xor(tmax, 32));

      // defer-max (T13): rescale only when max grew by > ~8/ln2 (log2 domain)
      if (!__all(tmax <= mrun + 11.54f)) {
        const float mn = fmaxf(mrun, tmax);
        const float corr = exp2a(mrun - mn);
        mrun = mn;
        lrun *= corr;
#pragma unroll
        for (int r = 0; r < 16; ++r) { O0[r] *= corr; O1[r] *= corr; }
      }
      float rsum = 0.f;
#pragma unroll
      for (int r = 0; r < 16; ++r) { p0[r] = exp2a(p0[r] - mrun); rsum += p0[r]; }
#pragma unroll
      for (int r = 0; r < 16; ++r) { p1[r] = exp2a(p1[r] - mrun); rsum += p1[r]; }
      rsum += __shfl_xor(rsum, 32);
      lrun += rsum;

      // pack P -> bf16 (cvt_pk) and build PV B-operand frags (P^T)
      bf16x8 Ub[4];
#pragma unroll
      for (int s = 0; s < 2; ++s) {
        unsigned pu[4][2];
#pragma unroll
        for (int m = 0; m < 4; ++m)
#pragma unroll
          for (int c = 0; c < 2; ++c)
            pu[m][c] = s ? cvtpk(p1[4 * m + 2 * c], p1[4 * m + 2 * c + 1])
                         : cvtpk(p0[4 * m + 2 * c], p0[4 * m + 2 * c + 1]);
#pragma unroll
        for (int tt = 0; tt < 2; ++tt) {
          unsigned s0v = hi ? pu[2 * tt][0] : pu[2 * tt + 1][0];
          unsigned s1v = hi ? pu[2 * tt][1] : pu[2 * tt + 1][1];
          unsigned r0 = __shfl_xor(s0v, 32);
          unsigned r1 = __shfl_xor(s1v, 32);
          union { unsigned u[4]; bf16x8 v; } U;
          U.u[0] = hi ? r0 : pu[2 * tt][0];
          U.u[1] = hi ? r1 : pu[2 * tt][1];
          U.u[2] = hi ? pu[2 * tt + 1][0] : r0;
          U.u[3] = hi ? pu[2 * tt + 1][1] : r1;
          Ub[s * 2 + tt] = U.v;
        }
      }

      // PV: O^T[d][q] += V^T_frag x P^T_frag, plain b128 frag reads
      __builtin_amdgcn_s_setprio(1);
#pragma unroll
      for (int ks = 0; ks < 4; ++ks) {
        bf16x8 vf0 = *reinterpret_cast<const bf16x8*>(&Vs[cur][(ks * 64 + lane) * 8]);
        O0 = __builtin_amdgcn_mfma_f32_32x32x16_bf16(vf0, Ub[ks], O0, 0, 0, 0);
        bf16x8 vf1 = *reinterpret_cast<const bf16x8*>(&Vs[cur][((4 + ks) * 64 + lane) * 8]);
        O1 = __builtin_amdgcn_mfma_f32_32x32x16_bf16(vf1, Ub[ks], O1, 0, 0, 0);
      }
      __builtin_amdgcn_s_setprio(0);
    }
    cur ^= 1;
  }

  // epilogue: O^T[d][q=lane&31] -> out rows; d = 32*half + 8m + 4hi + i
  const float inv = 1.0f / lrun;
  unsigned short* orow = out + (rowbase + q0w + l31) * 768 + h * 64;
#pragma unroll
  for (int half = 0; half < 2; ++half) {
    const f32x16& O = half ? O1 : O0;
#pragma unroll
    for (int m = 0; m < 4; ++m) {
      uint2 o2;
      o2.x = cvtpk(O[4 * m + 0] * inv, O[4 * m + 1] * inv);
      o2.y = cvtpk(O[4 * m + 2] * inv, O[4 * m + 3] * inv);
      *reinterpret_cast<uint2*>(orow + half * 32 + 8 * m + 4 * hi) = o2;
    }
  }
}

extern "C" void kernel_launch(void* const* d_in, const int* in_sizes, int n_in,
                              void* d_out, int out_size, void* d_ws, size_t ws_size,
                              hipStream_t stream) {
  const float* x = (const float*)d_in[0];
  const float* qkv_w = (const float*)d_in[1];
  const float* qkv_b = (const float*)d_in[2];
  const float* proj_w = (const float*)d_in[3];
  const float* proj_b = (const float*)d_in[4];
  float* out = (float*)d_out;

  unsigned short* x_bf = (unsigned short*)d_ws;            // 8192*768
  unsigned short* qw_bf = x_bf + (size_t)8192 * 768;       // 2304*768
  unsigned short* pw_bf = qw_bf + (size_t)2304 * 768;      // 768*768
  unsigned short* qkv = pw_bf + (size_t)768 * 768;         // 8192*2304
  unsigned short* attno = qkv + (size_t)8192 * 2304;       // 8192*768
  unsigned short* vtb = attno + (size_t)8192 * 768;        // 48*64*2048

  cast_f32_to_bf16<<<dim3(1024), dim3(256), 0, stream>>>(x, x_bf, 8192 * 768);
  cast_f32_to_bf16<<<dim3(512), dim3(256), 0, stream>>>(qkv_w, qw_bf, 2304 * 768);
  cast_f32_to_bf16<<<dim3(256), dim3(256), 0, stream>>>(proj_w, pw_bf, 768 * 768);

  gemm_bt_kernel<false><<<dim3(18, 64), dim3(256), 0, stream>>>(
      x_bf, qw_bf, qkv_b, qkv, 8192, 2304, 768, 2304);
  transpose_v<<<dim3(8, 48), dim3(256), 0, stream>>>(qkv, vtb);
  attn_kernel<<<dim3(768), dim3(256), 0, stream>>>(qkv, vtb, attno);
  gemm_bt_kernel<true><<<dim3(6, 64), dim3(256), 0, stream>>>(
      attno, pw_bf, proj_b, out, 8192, 768, 768, 768);
}